// Round 7
// baseline (555.401 us; speedup 1.0000x reference)
//
#include <hip/hip_runtime.h>

#define N_NODES 100000
#define N_EDGES 1200000
#define D 64

#define BSHIFT 10
#define NB ((N_NODES + 1023) >> BSHIFT)        // 98 buckets of 1024 nodes
#define EPB 2048                                // edges per partition block
#define P1_BLOCKS ((N_EDGES + EPB - 1) / EPB)   // 586
#define P2_CAP 16384                            // per-bucket edge capacity

// ---------------- Phase 1a: per-bucket edge counts ---------------------------
__global__ __launch_bounds__(256) void p1_count(const int* __restrict__ row,
                                                int* __restrict__ bucketCount) {
  __shared__ int h[NB];
  const int t = threadIdx.x;
  for (int i = t; i < NB; i += 256) h[i] = 0;
  __syncthreads();
  const int base = blockIdx.x * EPB;
#pragma unroll
  for (int i = 0; i < EPB / 256; ++i) {
    int e = base + i * 256 + t;
    if (e < N_EDGES) atomicAdd(&h[row[e] >> BSHIFT], 1);
  }
  __syncthreads();
  for (int i = t; i < NB; i += 256)
    if (h[i]) atomicAdd(&bucketCount[i], h[i]);
}

// ---------------- Phase 1b: scan bucket counts -> starts + cursors ----------
__global__ __launch_bounds__(128) void p1_scan(const int* __restrict__ bucketCount,
                                               int* __restrict__ bucketStart,
                                               int* __restrict__ cursor) {
  __shared__ int lds[128];
  const int t = threadIdx.x;
  int v = (t < NB) ? bucketCount[t] : 0;
  lds[t] = v;
  __syncthreads();
  for (int off = 1; off < 128; off <<= 1) {
    int add = (t >= off) ? lds[t - off] : 0;
    __syncthreads();
    lds[t] += add;
    __syncthreads();
  }
  if (t < NB) {
    int start = lds[t] - v;
    bucketStart[t] = start;
    cursor[t] = start;
  }
  if (t == NB - 1) bucketStart[NB] = lds[t];
}

// ---------------- Phase 1c: partition (row,col) pairs into buckets -----------
__global__ __launch_bounds__(256) void p1_scatter(
    const int* __restrict__ row, const int* __restrict__ col,
    int* __restrict__ cursor, unsigned long long* __restrict__ pairBuf) {
  __shared__ int h[NB];
  __shared__ int hexcl[NB];
  __shared__ int gbase[NB];
  __shared__ int scan_lds[128];
  __shared__ unsigned long long staged[EPB];
  const int t = threadIdx.x;
  for (int i = t; i < NB; i += 256) h[i] = 0;
  __syncthreads();
  const int base = blockIdx.x * EPB;
  const int cnt = min(EPB, N_EDGES - base);

  int myrank[EPB / 256];
  int mybkt[EPB / 256];
  unsigned long long mypair[EPB / 256];
#pragma unroll
  for (int i = 0; i < EPB / 256; ++i) {
    int e = base + i * 256 + t;
    if (e < N_EDGES) {
      unsigned r = (unsigned)row[e];
      unsigned c = (unsigned)col[e];
      int b = (int)(r >> BSHIFT);
      mybkt[i] = b;
      mypair[i] = ((unsigned long long)r << 32) | c;
      myrank[i] = atomicAdd(&h[b], 1);
    } else {
      mybkt[i] = -1;
    }
  }
  __syncthreads();
  int v = 0;
  if (t < 128) { v = (t < NB) ? h[t] : 0; scan_lds[t] = v; }
  __syncthreads();
  for (int off = 1; off < 128; off <<= 1) {
    int add = (t >= off && t < 128) ? scan_lds[t - off] : 0;
    __syncthreads();
    if (t < 128) scan_lds[t] += add;
    __syncthreads();
  }
  if (t < NB) {
    hexcl[t] = scan_lds[t] - v;
    gbase[t] = (h[t] > 0) ? atomicAdd(&cursor[t], h[t]) : 0;
  }
  __syncthreads();
#pragma unroll
  for (int i = 0; i < EPB / 256; ++i)
    if (mybkt[i] >= 0) staged[hexcl[mybkt[i]] + myrank[i]] = mypair[i];
  __syncthreads();
  for (int i = t; i < cnt; i += 256) {
    unsigned long long p = staged[i];
    int b = (int)(p >> (32 + BSHIFT));
    pairBuf[gbase[b] + (i - hexcl[b])] = p;
  }
}

// ---------------- Phase 2: per-bucket local CSR ------------------------------
__global__ __launch_bounds__(1024) void p2_csr(
    const unsigned long long* __restrict__ pairBuf,
    const int* __restrict__ bucketStart,
    int* __restrict__ ends, int* __restrict__ sortedCol) {
  __shared__ int hist[1024];
  __shared__ int sc[1024];
  __shared__ unsigned short rankLDS[P2_CAP];
  const int t = threadIdx.x;
  const int b = blockIdx.x;
  const int base = bucketStart[b];
  const int cnt = min(bucketStart[b + 1] - base, P2_CAP);
  hist[t] = 0;
  __syncthreads();
  for (int i = t; i < cnt; i += 1024) {
    int lr = (int)((pairBuf[base + i] >> 32) & ((1 << BSHIFT) - 1));
    rankLDS[i] = (unsigned short)atomicAdd(&hist[lr], 1);
  }
  __syncthreads();
  int v = hist[t];
  sc[t] = v;
  __syncthreads();
  for (int off = 1; off < 1024; off <<= 1) {
    int add = (t >= off) ? sc[t - off] : 0;
    __syncthreads();
    sc[t] += add;
    __syncthreads();
  }
  const int node = (b << BSHIFT) + t;
  if (node < N_NODES) ends[node] = base + sc[t];
  const int excl = sc[t] - v;
  __syncthreads();
  sc[t] = excl;
  __syncthreads();
  for (int i = t; i < cnt; i += 1024) {
    unsigned long long p = pairBuf[base + i];
    int lr = (int)((p >> 32) & ((1 << BSHIFT) - 1));
    sortedCol[base + sc[lr] + (int)rankLDS[i]] = (int)(unsigned)p;
  }
}

// ---------------- Mean aggregation: one wave per node, float4 gathers --------
__global__ __launch_bounds__(256) void sage_agg(
    const float* __restrict__ xin, const int* __restrict__ ends,
    const int* __restrict__ sortedCol, float* __restrict__ agg, int n) {
  const int lane = threadIdx.x & 63;
  const int g = lane >> 4;
  const int fq = lane & 15;
  const int gwave = (blockIdx.x * blockDim.x + threadIdx.x) >> 6;
  const int nwaves = (gridDim.x * blockDim.x) >> 6;

  for (int r = gwave; r < n; r += nwaves) {
    const int start = (r == 0) ? 0 : ends[r - 1];
    const int end = ends[r];
    const int deg = end - start;
    float4 acc = make_float4(0.f, 0.f, 0.f, 0.f);

    for (int base = start; base < end; base += 64) {
      const int m = min(64, end - base);
      const int cv = (lane < m) ? sortedCol[base + lane] : 0;
      int j = 0;
      for (; j + 16 <= m; j += 16) {
        const int c0 = __shfl(cv, j + 0 + g);
        const int c1 = __shfl(cv, j + 4 + g);
        const int c2 = __shfl(cv, j + 8 + g);
        const int c3 = __shfl(cv, j + 12 + g);
        const float4 v0 = *(const float4*)(xin + (size_t)c0 * D + fq * 4);
        const float4 v1 = *(const float4*)(xin + (size_t)c1 * D + fq * 4);
        const float4 v2 = *(const float4*)(xin + (size_t)c2 * D + fq * 4);
        const float4 v3 = *(const float4*)(xin + (size_t)c3 * D + fq * 4);
        acc.x += (v0.x + v1.x) + (v2.x + v3.x);
        acc.y += (v0.y + v1.y) + (v2.y + v3.y);
        acc.z += (v0.z + v1.z) + (v2.z + v3.z);
        acc.w += (v0.w + v1.w) + (v2.w + v3.w);
      }
      for (; j < m; j += 4) {
        const int idx = j + g;
        const int c = __shfl(cv, (idx < m) ? idx : 0);
        if (idx < m) {
          const float4 v = *(const float4*)(xin + (size_t)c * D + fq * 4);
          acc.x += v.x; acc.y += v.y; acc.z += v.z; acc.w += v.w;
        }
      }
    }
    acc.x += __shfl_xor(acc.x, 16); acc.x += __shfl_xor(acc.x, 32);
    acc.y += __shfl_xor(acc.y, 16); acc.y += __shfl_xor(acc.y, 32);
    acc.z += __shfl_xor(acc.z, 16); acc.z += __shfl_xor(acc.z, 32);
    acc.w += __shfl_xor(acc.w, 16); acc.w += __shfl_xor(acc.w, 32);
    if (g == 0) {
      const float s = 1.0f / (float)max(deg, 1);
      float4 o;
      o.x = acc.x * s; o.y = acc.y * s; o.z = acc.z * s; o.w = acc.w * s;
      *(float4*)(agg + (size_t)r * D + fq * 4) = o;
    }
  }
}

// ---------------- Concat-matmul: out = act(b + x@Wtop + agg@Wbot) ------------
// W transposed in LDS: Wl[h][feat][k] (pad 66 -> ds_read_b64, ~2-way).
// Each wave owns 8-row chunks; k-outer loop: one W read serves 8 rows' FMAs.
// Per chunk: 64 ds_read_b64 + 256 float4 loads + 1024 v_fma. No per-lane W
// array (no spill/remat ambiguity), no inter-wave dependency.
#define WPAD 66
__global__ __launch_bounds__(256) void sage_mm(
    const float* __restrict__ xin, const float* __restrict__ agg,
    const float* __restrict__ W, const float* __restrict__ b,
    float* __restrict__ out, int n, int doRelu) {
  __shared__ float Wl[2][64][WPAD];
  const int t = threadIdx.x;
  // stage W transposed: Wl[h][f][k] = W[(h*64+k)*64 + f]
  for (int idx = t; idx < 128 * 64; idx += 256) {
    const int krow = idx >> 6;        // 0..127
    const int f = idx & 63;
    const float v = W[idx];
    const int h = krow >> 6;
    const int k = krow & 63;
    Wl[h][f][k] = v;
  }
  __syncthreads();

  const int lane = t & 63;
  int gwave = (blockIdx.x * blockDim.x + t) >> 6;
  const int nwaves = (gridDim.x * blockDim.x) >> 6;
  const float breg = b[lane];
  const int nChunks = (n + 7) >> 3;

  for (int chunk = gwave; chunk < nChunks; chunk += nwaves) {
    const int rbase = __builtin_amdgcn_readfirstlane(chunk << 3);
    const int rcnt = min(8, n - rbase);

    float acc[8];
#pragma unroll
    for (int j = 0; j < 8; ++j) acc[j] = breg;

    // half 0: x against Wl[0]; half 1: agg against Wl[1]
#pragma unroll
    for (int h = 0; h < 2; ++h) {
      const float* __restrict__ src = (h == 0) ? xin : agg;
      const float* wbase = &Wl[h][lane][0];
#pragma unroll
      for (int kb = 0; kb < 8; ++kb) {
        float wk[8];
#pragma unroll
        for (int p = 0; p < 4; ++p) {
          const float2 wv = *(const float2*)(wbase + kb * 8 + 2 * p);
          wk[2 * p] = wv.x;
          wk[2 * p + 1] = wv.y;
        }
#pragma unroll
        for (int j = 0; j < 8; ++j) {
          if (j < rcnt) {
            const float4* xr =
                (const float4*)(src + (size_t)(rbase + j) * D + kb * 8);
            const float4 a0 = xr[0];
            const float4 a1 = xr[1];
            acc[j] = fmaf(a0.x, wk[0], acc[j]);
            acc[j] = fmaf(a0.y, wk[1], acc[j]);
            acc[j] = fmaf(a0.z, wk[2], acc[j]);
            acc[j] = fmaf(a0.w, wk[3], acc[j]);
            acc[j] = fmaf(a1.x, wk[4], acc[j]);
            acc[j] = fmaf(a1.y, wk[5], acc[j]);
            acc[j] = fmaf(a1.z, wk[6], acc[j]);
            acc[j] = fmaf(a1.w, wk[7], acc[j]);
          }
        }
      }
    }

#pragma unroll
    for (int j = 0; j < 8; ++j) {
      if (j < rcnt) {
        float v = acc[j];
        if (doRelu) v = fmaxf(v, 0.0f);
        out[(size_t)(rbase + j) * D + lane] = v;
      }
    }
  }
}

extern "C" void kernel_launch(void* const* d_in, const int* in_sizes, int n_in,
                              void* d_out, int out_size, void* d_ws, size_t ws_size,
                              hipStream_t stream) {
  const float* x  = (const float*)d_in[0];
  const int*   ei = (const int*)d_in[1];
  const float* W1 = (const float*)d_in[2];
  const float* b1 = (const float*)d_in[3];
  const float* W2 = (const float*)d_in[4];
  const float* b2 = (const float*)d_in[5];
  float* out = (float*)d_out;

  const int* row = ei;            // edge_index[0]
  const int* col = ei + N_EDGES;  // edge_index[1]

  char* ws = (char*)d_ws;
  int* endsArr = (int*)ws;
  size_t off = ((size_t)N_NODES * sizeof(int) + 4095) & ~(size_t)4095;
  int* sortedCol = (int*)(ws + off);
  off += ((size_t)N_EDGES * sizeof(int) + 4095) & ~(size_t)4095;
  int* bucketCount = (int*)(ws + off);
  int* bucketStart = bucketCount + 128;
  int* cursor = bucketStart + 256;
  off += 4096;
  unsigned long long* pairBuf = (unsigned long long*)(ws + off);
  float* aggbuf = (float*)(ws + off);  // union: pairBuf dead before first sage_agg

  hipMemsetAsync(bucketCount, 0, NB * sizeof(int), stream);

  // ---- CSR build: bucketed two-phase partition ----
  p1_count<<<P1_BLOCKS, 256, 0, stream>>>(row, bucketCount);
  p1_scan<<<1, 128, 0, stream>>>(bucketCount, bucketStart, cursor);
  p1_scatter<<<P1_BLOCKS, 256, 0, stream>>>(row, col, cursor, pairBuf);
  p2_csr<<<NB, 1024, 0, stream>>>(pairBuf, bucketStart, endsArr, sortedCol);

  // ---- Layer 1: h = relu(concat(x, mean(x)) @ W1 + b1), h in d_out ----
  sage_agg<<<2048, 256, 0, stream>>>(x, endsArr, sortedCol, aggbuf, N_NODES);
  sage_mm<<<1024, 256, 0, stream>>>(x, aggbuf, W1, b1, out, N_NODES, 1);

  // ---- Layer 2: out = concat(h, mean(h)) @ W2 + b2 (in place over h) ----
  sage_agg<<<2048, 256, 0, stream>>>(out, endsArr, sortedCol, aggbuf, N_NODES);
  sage_mm<<<1024, 256, 0, stream>>>(out, aggbuf, W2, b2, out, N_NODES, 0);
}

// Round 8
// 457.483 us; speedup vs baseline: 1.2140x; 1.2140x over previous
//
#include <hip/hip_runtime.h>

#define N_NODES 100000
#define N_EDGES 1200000
#define D 64

#define BSHIFT 10
#define NB ((N_NODES + 1023) >> BSHIFT)        // 98 buckets of 1024 nodes
#define EPB 2048                                // edges per partition block
#define P1_BLOCKS ((N_EDGES + EPB - 1) / EPB)   // 586
#define P2_CAP 16384                            // per-bucket edge capacity

// ---------------- Phase 1a: per-bucket edge counts ---------------------------
__global__ __launch_bounds__(256) void p1_count(const int* __restrict__ row,
                                                int* __restrict__ bucketCount) {
  __shared__ int h[NB];
  const int t = threadIdx.x;
  for (int i = t; i < NB; i += 256) h[i] = 0;
  __syncthreads();
  const int base = blockIdx.x * EPB;
#pragma unroll
  for (int i = 0; i < EPB / 256; ++i) {
    int e = base + i * 256 + t;
    if (e < N_EDGES) atomicAdd(&h[row[e] >> BSHIFT], 1);
  }
  __syncthreads();
  for (int i = t; i < NB; i += 256)
    if (h[i]) atomicAdd(&bucketCount[i], h[i]);
}

// ---------------- Phase 1b: scan bucket counts -> starts + cursors ----------
__global__ __launch_bounds__(128) void p1_scan(const int* __restrict__ bucketCount,
                                               int* __restrict__ bucketStart,
                                               int* __restrict__ cursor) {
  __shared__ int lds[128];
  const int t = threadIdx.x;
  int v = (t < NB) ? bucketCount[t] : 0;
  lds[t] = v;
  __syncthreads();
  for (int off = 1; off < 128; off <<= 1) {
    int add = (t >= off) ? lds[t - off] : 0;
    __syncthreads();
    lds[t] += add;
    __syncthreads();
  }
  if (t < NB) {
    int start = lds[t] - v;
    bucketStart[t] = start;
    cursor[t] = start;
  }
  if (t == NB - 1) bucketStart[NB] = lds[t];
}

// ---------------- Phase 1c: partition (row,col) pairs into buckets -----------
__global__ __launch_bounds__(256) void p1_scatter(
    const int* __restrict__ row, const int* __restrict__ col,
    int* __restrict__ cursor, unsigned long long* __restrict__ pairBuf) {
  __shared__ int h[NB];
  __shared__ int hexcl[NB];
  __shared__ int gbase[NB];
  __shared__ int scan_lds[128];
  __shared__ unsigned long long staged[EPB];
  const int t = threadIdx.x;
  for (int i = t; i < NB; i += 256) h[i] = 0;
  __syncthreads();
  const int base = blockIdx.x * EPB;
  const int cnt = min(EPB, N_EDGES - base);

  int myrank[EPB / 256];
  int mybkt[EPB / 256];
  unsigned long long mypair[EPB / 256];
#pragma unroll
  for (int i = 0; i < EPB / 256; ++i) {
    int e = base + i * 256 + t;
    if (e < N_EDGES) {
      unsigned r = (unsigned)row[e];
      unsigned c = (unsigned)col[e];
      int b = (int)(r >> BSHIFT);
      mybkt[i] = b;
      mypair[i] = ((unsigned long long)r << 32) | c;
      myrank[i] = atomicAdd(&h[b], 1);
    } else {
      mybkt[i] = -1;
    }
  }
  __syncthreads();
  int v = 0;
  if (t < 128) { v = (t < NB) ? h[t] : 0; scan_lds[t] = v; }
  __syncthreads();
  for (int off = 1; off < 128; off <<= 1) {
    int add = (t >= off && t < 128) ? scan_lds[t - off] : 0;
    __syncthreads();
    if (t < 128) scan_lds[t] += add;
    __syncthreads();
  }
  if (t < NB) {
    hexcl[t] = scan_lds[t] - v;
    gbase[t] = (h[t] > 0) ? atomicAdd(&cursor[t], h[t]) : 0;
  }
  __syncthreads();
#pragma unroll
  for (int i = 0; i < EPB / 256; ++i)
    if (mybkt[i] >= 0) staged[hexcl[mybkt[i]] + myrank[i]] = mypair[i];
  __syncthreads();
  for (int i = t; i < cnt; i += 256) {
    unsigned long long p = staged[i];
    int b = (int)(p >> (32 + BSHIFT));
    pairBuf[gbase[b] + (i - hexcl[b])] = p;
  }
}

// ---------------- Phase 2: per-bucket local CSR ------------------------------
__global__ __launch_bounds__(1024) void p2_csr(
    const unsigned long long* __restrict__ pairBuf,
    const int* __restrict__ bucketStart,
    int* __restrict__ ends, int* __restrict__ sortedCol) {
  __shared__ int hist[1024];
  __shared__ int sc[1024];
  __shared__ unsigned short rankLDS[P2_CAP];
  const int t = threadIdx.x;
  const int b = blockIdx.x;
  const int base = bucketStart[b];
  const int cnt = min(bucketStart[b + 1] - base, P2_CAP);
  hist[t] = 0;
  __syncthreads();
  for (int i = t; i < cnt; i += 1024) {
    int lr = (int)((pairBuf[base + i] >> 32) & ((1 << BSHIFT) - 1));
    rankLDS[i] = (unsigned short)atomicAdd(&hist[lr], 1);
  }
  __syncthreads();
  int v = hist[t];
  sc[t] = v;
  __syncthreads();
  for (int off = 1; off < 1024; off <<= 1) {
    int add = (t >= off) ? sc[t - off] : 0;
    __syncthreads();
    sc[t] += add;
    __syncthreads();
  }
  const int node = (b << BSHIFT) + t;
  if (node < N_NODES) ends[node] = base + sc[t];
  const int excl = sc[t] - v;
  __syncthreads();
  sc[t] = excl;
  __syncthreads();
  for (int i = t; i < cnt; i += 1024) {
    unsigned long long p = pairBuf[base + i];
    int lr = (int)((p >> 32) & ((1 << BSHIFT) - 1));
    sortedCol[base + sc[lr] + (int)rankLDS[i]] = (int)(unsigned)p;
  }
}

// ---------------- Mean aggregation: one wave per node, float4 gathers --------
__global__ __launch_bounds__(256) void sage_agg(
    const float* __restrict__ xin, const int* __restrict__ ends,
    const int* __restrict__ sortedCol, float* __restrict__ agg, int n) {
  const int lane = threadIdx.x & 63;
  const int g = lane >> 4;
  const int fq = lane & 15;
  const int gwave = (blockIdx.x * blockDim.x + threadIdx.x) >> 6;
  const int nwaves = (gridDim.x * blockDim.x) >> 6;

  for (int r = gwave; r < n; r += nwaves) {
    const int start = (r == 0) ? 0 : ends[r - 1];
    const int end = ends[r];
    const int deg = end - start;
    float4 acc = make_float4(0.f, 0.f, 0.f, 0.f);

    for (int base = start; base < end; base += 64) {
      const int m = min(64, end - base);
      const int cv = (lane < m) ? sortedCol[base + lane] : 0;
      int j = 0;
      for (; j + 16 <= m; j += 16) {
        const int c0 = __shfl(cv, j + 0 + g);
        const int c1 = __shfl(cv, j + 4 + g);
        const int c2 = __shfl(cv, j + 8 + g);
        const int c3 = __shfl(cv, j + 12 + g);
        const float4 v0 = *(const float4*)(xin + (size_t)c0 * D + fq * 4);
        const float4 v1 = *(const float4*)(xin + (size_t)c1 * D + fq * 4);
        const float4 v2 = *(const float4*)(xin + (size_t)c2 * D + fq * 4);
        const float4 v3 = *(const float4*)(xin + (size_t)c3 * D + fq * 4);
        acc.x += (v0.x + v1.x) + (v2.x + v3.x);
        acc.y += (v0.y + v1.y) + (v2.y + v3.y);
        acc.z += (v0.z + v1.z) + (v2.z + v3.z);
        acc.w += (v0.w + v1.w) + (v2.w + v3.w);
      }
      for (; j < m; j += 4) {
        const int idx = j + g;
        const int c = __shfl(cv, (idx < m) ? idx : 0);
        if (idx < m) {
          const float4 v = *(const float4*)(xin + (size_t)c * D + fq * 4);
          acc.x += v.x; acc.y += v.y; acc.z += v.z; acc.w += v.w;
        }
      }
    }
    acc.x += __shfl_xor(acc.x, 16); acc.x += __shfl_xor(acc.x, 32);
    acc.y += __shfl_xor(acc.y, 16); acc.y += __shfl_xor(acc.y, 32);
    acc.z += __shfl_xor(acc.z, 16); acc.z += __shfl_xor(acc.z, 32);
    acc.w += __shfl_xor(acc.w, 16); acc.w += __shfl_xor(acc.w, 32);
    if (g == 0) {
      const float s = 1.0f / (float)max(deg, 1);
      float4 o;
      o.x = acc.x * s; o.y = acc.y * s; o.z = acc.z * s; o.w = acc.w * s;
      *(float4*)(agg + (size_t)r * D + fq * 4) = o;
    }
  }
}

// ---------------- Concat-matmul: out = act(b + x@Wtop + agg@Wbot) ------------
// R5 structure + two fixes:
//  (1) asm-pin wreg[128] so the compiler CANNOT rematerialize/sink the W loads
//      (R5's VGPR_Count=72 proved it did; pin forces true residency).
//  (2) 4 rows per wave: each wreg[k] broadcast serves 4 FMAs -> readlane cost
//      amortized, per-group inner loop is 1024 pure VALU ops.
__global__ __launch_bounds__(256, 2) void sage_mm(
    const float* __restrict__ xin, const float* __restrict__ agg,
    const float* __restrict__ W, const float* __restrict__ b,
    float* __restrict__ out, int n, int doRelu) {
  const int lane = threadIdx.x & 63;
  const int gwave = (blockIdx.x * blockDim.x + threadIdx.x) >> 6;
  const int nwaves = (gridDim.x * blockDim.x) >> 6;

  float wreg[128];
#pragma unroll
  for (int i = 0; i < 128; ++i) wreg[i] = W[(size_t)i * D + lane];
#pragma unroll
  for (int i = 0; i < 128; ++i) asm volatile("" : "+v"(wreg[i]));
  const float breg = b[lane];

  const int ngroups = (n + 3) >> 2;
  for (int gidx = gwave; gidx < ngroups; gidx += nwaves) {
    const int r0 = gidx << 2;
    const int rcnt = min(4, n - r0);

    float xv[4], av[4];
#pragma unroll
    for (int j = 0; j < 4; ++j) {
      const int rr = (j < rcnt) ? (r0 + j) : r0;
      xv[j] = xin[(size_t)rr * D + lane];
      av[j] = agg[(size_t)rr * D + lane];
    }

    float acc[4] = {breg, breg, breg, breg};
#pragma unroll
    for (int i = 0; i < 64; ++i) {
#pragma unroll
      for (int j = 0; j < 4; ++j) {
        const float xs =
            __uint_as_float(__builtin_amdgcn_readlane(__float_as_uint(xv[j]), i));
        acc[j] = fmaf(xs, wreg[i], acc[j]);
      }
#pragma unroll
      for (int j = 0; j < 4; ++j) {
        const float as =
            __uint_as_float(__builtin_amdgcn_readlane(__float_as_uint(av[j]), i));
        acc[j] = fmaf(as, wreg[64 + i], acc[j]);
      }
    }

#pragma unroll
    for (int j = 0; j < 4; ++j) {
      if (j < rcnt) {
        float v = acc[j];
        if (doRelu) v = fmaxf(v, 0.0f);
        out[(size_t)(r0 + j) * D + lane] = v;
      }
    }
  }
}

extern "C" void kernel_launch(void* const* d_in, const int* in_sizes, int n_in,
                              void* d_out, int out_size, void* d_ws, size_t ws_size,
                              hipStream_t stream) {
  const float* x  = (const float*)d_in[0];
  const int*   ei = (const int*)d_in[1];
  const float* W1 = (const float*)d_in[2];
  const float* b1 = (const float*)d_in[3];
  const float* W2 = (const float*)d_in[4];
  const float* b2 = (const float*)d_in[5];
  float* out = (float*)d_out;

  const int* row = ei;            // edge_index[0]
  const int* col = ei + N_EDGES;  // edge_index[1]

  char* ws = (char*)d_ws;
  int* endsArr = (int*)ws;
  size_t off = ((size_t)N_NODES * sizeof(int) + 4095) & ~(size_t)4095;
  int* sortedCol = (int*)(ws + off);
  off += ((size_t)N_EDGES * sizeof(int) + 4095) & ~(size_t)4095;
  int* bucketCount = (int*)(ws + off);
  int* bucketStart = bucketCount + 128;
  int* cursor = bucketStart + 256;
  off += 4096;
  unsigned long long* pairBuf = (unsigned long long*)(ws + off);
  float* aggbuf = (float*)(ws + off);  // union: pairBuf dead before first sage_agg

  hipMemsetAsync(bucketCount, 0, NB * sizeof(int), stream);

  // ---- CSR build: bucketed two-phase partition ----
  p1_count<<<P1_BLOCKS, 256, 0, stream>>>(row, bucketCount);
  p1_scan<<<1, 128, 0, stream>>>(bucketCount, bucketStart, cursor);
  p1_scatter<<<P1_BLOCKS, 256, 0, stream>>>(row, col, cursor, pairBuf);
  p2_csr<<<NB, 1024, 0, stream>>>(pairBuf, bucketStart, endsArr, sortedCol);

  // ---- Layer 1: h = relu(concat(x, mean(x)) @ W1 + b1), h in d_out ----
  sage_agg<<<2048, 256, 0, stream>>>(x, endsArr, sortedCol, aggbuf, N_NODES);
  sage_mm<<<1024, 256, 0, stream>>>(x, aggbuf, W1, b1, out, N_NODES, 1);

  // ---- Layer 2: out = concat(h, mean(h)) @ W2 + b2 (in place over h) ----
  sage_agg<<<2048, 256, 0, stream>>>(out, endsArr, sortedCol, aggbuf, N_NODES);
  sage_mm<<<1024, 256, 0, stream>>>(out, aggbuf, W2, b2, out, N_NODES, 0);
}

// Round 9
// 265.093 us; speedup vs baseline: 2.0951x; 1.7257x over previous
//
#include <hip/hip_runtime.h>

#define N_NODES 100000
#define N_EDGES 1200000
#define D 64

#define BSHIFT 10
#define NB ((N_NODES + 1023) >> BSHIFT)        // 98 buckets of 1024 nodes
#define EPB 2048                                // edges per partition block
#define P1_BLOCKS ((N_EDGES + EPB - 1) / EPB)   // 586
#define P2_CAP 16384                            // per-bucket edge capacity

typedef short bf16x8 __attribute__((ext_vector_type(8)));
typedef float f32x4 __attribute__((ext_vector_type(4)));

__device__ __forceinline__ short f2bf(float x) {
  unsigned u = __float_as_uint(x);
  unsigned r = (u + 0x7FFFu + ((u >> 16) & 1u)) >> 16;  // RNE
  return (short)r;
}
__device__ __forceinline__ float bf2f(short b) {
  return __uint_as_float(((unsigned)(unsigned short)b) << 16);
}

// ---------------- Phase 1a: per-bucket edge counts ---------------------------
__global__ __launch_bounds__(256) void p1_count(const int* __restrict__ row,
                                                int* __restrict__ bucketCount) {
  __shared__ int h[NB];
  const int t = threadIdx.x;
  for (int i = t; i < NB; i += 256) h[i] = 0;
  __syncthreads();
  const int base = blockIdx.x * EPB;
#pragma unroll
  for (int i = 0; i < EPB / 256; ++i) {
    int e = base + i * 256 + t;
    if (e < N_EDGES) atomicAdd(&h[row[e] >> BSHIFT], 1);
  }
  __syncthreads();
  for (int i = t; i < NB; i += 256)
    if (h[i]) atomicAdd(&bucketCount[i], h[i]);
}

// ---------------- Phase 1b: scan bucket counts -> starts + cursors ----------
__global__ __launch_bounds__(128) void p1_scan(const int* __restrict__ bucketCount,
                                               int* __restrict__ bucketStart,
                                               int* __restrict__ cursor) {
  __shared__ int lds[128];
  const int t = threadIdx.x;
  int v = (t < NB) ? bucketCount[t] : 0;
  lds[t] = v;
  __syncthreads();
  for (int off = 1; off < 128; off <<= 1) {
    int add = (t >= off) ? lds[t - off] : 0;
    __syncthreads();
    lds[t] += add;
    __syncthreads();
  }
  if (t < NB) {
    int start = lds[t] - v;
    bucketStart[t] = start;
    cursor[t] = start;
  }
  if (t == NB - 1) bucketStart[NB] = lds[t];
}

// ---------------- Phase 1c: partition (row,col) pairs into buckets -----------
__global__ __launch_bounds__(256) void p1_scatter(
    const int* __restrict__ row, const int* __restrict__ col,
    int* __restrict__ cursor, unsigned long long* __restrict__ pairBuf) {
  __shared__ int h[NB];
  __shared__ int hexcl[NB];
  __shared__ int gbase[NB];
  __shared__ int scan_lds[128];
  __shared__ unsigned long long staged[EPB];
  const int t = threadIdx.x;
  for (int i = t; i < NB; i += 256) h[i] = 0;
  __syncthreads();
  const int base = blockIdx.x * EPB;
  const int cnt = min(EPB, N_EDGES - base);

  int myrank[EPB / 256];
  int mybkt[EPB / 256];
  unsigned long long mypair[EPB / 256];
#pragma unroll
  for (int i = 0; i < EPB / 256; ++i) {
    int e = base + i * 256 + t;
    if (e < N_EDGES) {
      unsigned r = (unsigned)row[e];
      unsigned c = (unsigned)col[e];
      int b = (int)(r >> BSHIFT);
      mybkt[i] = b;
      mypair[i] = ((unsigned long long)r << 32) | c;
      myrank[i] = atomicAdd(&h[b], 1);
    } else {
      mybkt[i] = -1;
    }
  }
  __syncthreads();
  int v = 0;
  if (t < 128) { v = (t < NB) ? h[t] : 0; scan_lds[t] = v; }
  __syncthreads();
  for (int off = 1; off < 128; off <<= 1) {
    int add = (t >= off && t < 128) ? scan_lds[t - off] : 0;
    __syncthreads();
    if (t < 128) scan_lds[t] += add;
    __syncthreads();
  }
  if (t < NB) {
    hexcl[t] = scan_lds[t] - v;
    gbase[t] = (h[t] > 0) ? atomicAdd(&cursor[t], h[t]) : 0;
  }
  __syncthreads();
#pragma unroll
  for (int i = 0; i < EPB / 256; ++i)
    if (mybkt[i] >= 0) staged[hexcl[mybkt[i]] + myrank[i]] = mypair[i];
  __syncthreads();
  for (int i = t; i < cnt; i += 256) {
    unsigned long long p = staged[i];
    int b = (int)(p >> (32 + BSHIFT));
    pairBuf[gbase[b] + (i - hexcl[b])] = p;
  }
}

// ---------------- Phase 2: per-bucket local CSR ------------------------------
__global__ __launch_bounds__(1024) void p2_csr(
    const unsigned long long* __restrict__ pairBuf,
    const int* __restrict__ bucketStart,
    int* __restrict__ ends, int* __restrict__ sortedCol) {
  __shared__ int hist[1024];
  __shared__ int sc[1024];
  __shared__ unsigned short rankLDS[P2_CAP];
  const int t = threadIdx.x;
  const int b = blockIdx.x;
  const int base = bucketStart[b];
  const int cnt = min(bucketStart[b + 1] - base, P2_CAP);
  hist[t] = 0;
  __syncthreads();
  for (int i = t; i < cnt; i += 1024) {
    int lr = (int)((pairBuf[base + i] >> 32) & ((1 << BSHIFT) - 1));
    rankLDS[i] = (unsigned short)atomicAdd(&hist[lr], 1);
  }
  __syncthreads();
  int v = hist[t];
  sc[t] = v;
  __syncthreads();
  for (int off = 1; off < 1024; off <<= 1) {
    int add = (t >= off) ? sc[t - off] : 0;
    __syncthreads();
    sc[t] += add;
    __syncthreads();
  }
  const int node = (b << BSHIFT) + t;
  if (node < N_NODES) ends[node] = base + sc[t];
  const int excl = sc[t] - v;
  __syncthreads();
  sc[t] = excl;
  __syncthreads();
  for (int i = t; i < cnt; i += 1024) {
    unsigned long long p = pairBuf[base + i];
    int lr = (int)((p >> 32) & ((1 << BSHIFT) - 1));
    sortedCol[base + sc[lr] + (int)rankLDS[i]] = (int)(unsigned)p;
  }
}

// ---------------- Mean aggregation: one wave per node, float4 gathers --------
__global__ __launch_bounds__(256) void sage_agg(
    const float* __restrict__ xin, const int* __restrict__ ends,
    const int* __restrict__ sortedCol, float* __restrict__ agg, int n) {
  const int lane = threadIdx.x & 63;
  const int g = lane >> 4;
  const int fq = lane & 15;
  const int gwave = (blockIdx.x * blockDim.x + threadIdx.x) >> 6;
  const int nwaves = (gridDim.x * blockDim.x) >> 6;

  for (int r = gwave; r < n; r += nwaves) {
    const int start = (r == 0) ? 0 : ends[r - 1];
    const int end = ends[r];
    const int deg = end - start;
    float4 acc = make_float4(0.f, 0.f, 0.f, 0.f);

    for (int base = start; base < end; base += 64) {
      const int m = min(64, end - base);
      const int cv = (lane < m) ? sortedCol[base + lane] : 0;
      int j = 0;
      for (; j + 16 <= m; j += 16) {
        const int c0 = __shfl(cv, j + 0 + g);
        const int c1 = __shfl(cv, j + 4 + g);
        const int c2 = __shfl(cv, j + 8 + g);
        const int c3 = __shfl(cv, j + 12 + g);
        const float4 v0 = *(const float4*)(xin + (size_t)c0 * D + fq * 4);
        const float4 v1 = *(const float4*)(xin + (size_t)c1 * D + fq * 4);
        const float4 v2 = *(const float4*)(xin + (size_t)c2 * D + fq * 4);
        const float4 v3 = *(const float4*)(xin + (size_t)c3 * D + fq * 4);
        acc.x += (v0.x + v1.x) + (v2.x + v3.x);
        acc.y += (v0.y + v1.y) + (v2.y + v3.y);
        acc.z += (v0.z + v1.z) + (v2.z + v3.z);
        acc.w += (v0.w + v1.w) + (v2.w + v3.w);
      }
      for (; j < m; j += 4) {
        const int idx = j + g;
        const int c = __shfl(cv, (idx < m) ? idx : 0);
        if (idx < m) {
          const float4 v = *(const float4*)(xin + (size_t)c * D + fq * 4);
          acc.x += v.x; acc.y += v.y; acc.z += v.z; acc.w += v.w;
        }
      }
    }
    acc.x += __shfl_xor(acc.x, 16); acc.x += __shfl_xor(acc.x, 32);
    acc.y += __shfl_xor(acc.y, 16); acc.y += __shfl_xor(acc.y, 32);
    acc.z += __shfl_xor(acc.z, 16); acc.z += __shfl_xor(acc.z, 32);
    acc.w += __shfl_xor(acc.w, 16); acc.w += __shfl_xor(acc.w, 32);
    if (g == 0) {
      const float s = 1.0f / (float)max(deg, 1);
      float4 o;
      o.x = acc.x * s; o.y = acc.y * s; o.z = acc.z * s; o.w = acc.w * s;
      *(float4*)(agg + (size_t)r * D + fq * 4) = o;
    }
  }
}

// ---------------- W pre-swizzle: fp32 W[128][64] -> bf16 hi/lo fragments -----
// Fragment layout (m89/m120-verified): for n-tile t (0..3), k-step s (0..3),
// lane l: B[k=(l>>4)*8+j][n=l&15] with global k = s*32+..., n = t*16+...
// Stored so a lane's 8 bf16 are contiguous 16B: index ((t*4+s)*64 + l)*8 + j.
__global__ __launch_bounds__(256) void w_swizzle(const float* __restrict__ W,
                                                 short* __restrict__ wh,
                                                 short* __restrict__ wl) {
  int i = blockIdx.x * blockDim.x + threadIdx.x;
  if (i >= 4 * 4 * 64 * 8) return;
  int j = i & 7;
  int l = (i >> 3) & 63;
  int s = (i >> 9) & 3;
  int t = i >> 11;
  int k = s * 32 + ((l >> 4) * 8) + j;
  int n = t * 16 + (l & 15);
  float v = W[k * 64 + n];
  short hb = f2bf(v);
  short lb = f2bf(v - bf2f(hb));
  wh[i] = hb;
  wl[i] = lb;
}

// ---------------- Concat-matmul via split-bf16 MFMA --------------------------
// C[100000,64] = concat(x,agg)[.,128] @ W[128,64] + b, split precision:
// C ≈ Xh·Wh + Xh·Wl + Xl·Wh (fp32 accum; error ~3e-4 << 1.78e-2 threshold).
// One wave per 16-row tile (100000 = 6250 tiles exactly). 48 MFMAs/tile.
__global__ __launch_bounds__(256) void sage_mm(
    const float* __restrict__ xin, const float* __restrict__ agg,
    const short* __restrict__ wh, const short* __restrict__ wl,
    const float* __restrict__ b, float* __restrict__ out, int doRelu) {
  const int lane = threadIdx.x & 63;
  const int m = lane & 15;
  const int q = lane >> 4;
  const int gwave = (blockIdx.x * blockDim.x + threadIdx.x) >> 6;
  const int nwaves = (gridDim.x * blockDim.x) >> 6;
  const int nTiles = N_NODES / 16;  // 6250

  for (int tile = gwave; tile < nTiles; tile += nwaves) {
    const int r0 = tile * 16;
    f32x4 acc[4];
#pragma unroll
    for (int t = 0; t < 4; ++t) {
      const float bv = b[t * 16 + m];
      acc[t][0] = bv; acc[t][1] = bv; acc[t][2] = bv; acc[t][3] = bv;
    }

#pragma unroll
    for (int s = 0; s < 4; ++s) {
      const float* __restrict__ src = (s < 2) ? xin : agg;
      const int kb = (s & 1) * 32 + q * 8;  // offset within the 64-wide row
      const float* rowp = src + (size_t)(r0 + m) * D + kb;
      const float4 a0 = *(const float4*)rowp;
      const float4 a1 = *(const float4*)(rowp + 4);
      const float f[8] = {a0.x, a0.y, a0.z, a0.w, a1.x, a1.y, a1.z, a1.w};
      bf16x8 Ah, Al;
#pragma unroll
      for (int j = 0; j < 8; ++j) {
        const short hb = f2bf(f[j]);
        Ah[j] = hb;
        Al[j] = f2bf(f[j] - bf2f(hb));
      }
#pragma unroll
      for (int t = 0; t < 4; ++t) {
        const int bi = ((t * 4 + s) * 64 + lane) * 8;
        const bf16x8 Bh = *(const bf16x8*)(wh + bi);
        const bf16x8 Bl = *(const bf16x8*)(wl + bi);
        acc[t] = __builtin_amdgcn_mfma_f32_16x16x32_bf16(Ah, Bh, acc[t], 0, 0, 0);
        acc[t] = __builtin_amdgcn_mfma_f32_16x16x32_bf16(Ah, Bl, acc[t], 0, 0, 0);
        acc[t] = __builtin_amdgcn_mfma_f32_16x16x32_bf16(Al, Bh, acc[t], 0, 0, 0);
      }
    }

    // C layout: col = t*16 + m, row = q*4 + rg
#pragma unroll
    for (int t = 0; t < 4; ++t) {
#pragma unroll
      for (int rg = 0; rg < 4; ++rg) {
        float v = acc[t][rg];
        if (doRelu) v = fmaxf(v, 0.0f);
        out[(size_t)(r0 + q * 4 + rg) * D + t * 16 + m] = v;
      }
    }
  }
}

extern "C" void kernel_launch(void* const* d_in, const int* in_sizes, int n_in,
                              void* d_out, int out_size, void* d_ws, size_t ws_size,
                              hipStream_t stream) {
  const float* x  = (const float*)d_in[0];
  const int*   ei = (const int*)d_in[1];
  const float* W1 = (const float*)d_in[2];
  const float* b1 = (const float*)d_in[3];
  const float* W2 = (const float*)d_in[4];
  const float* b2 = (const float*)d_in[5];
  float* out = (float*)d_out;

  const int* row = ei;            // edge_index[0]
  const int* col = ei + N_EDGES;  // edge_index[1]

  // ws layout:
  //   ends[N] | sortedCol[E] | bucket meta | w1h|w1l|w2h|w2l (4×16KB)
  //   | union{ pairBuf[E u64], aggbuf[N*64 f] }
  char* ws = (char*)d_ws;
  int* endsArr = (int*)ws;
  size_t off = ((size_t)N_NODES * sizeof(int) + 4095) & ~(size_t)4095;
  int* sortedCol = (int*)(ws + off);
  off += ((size_t)N_EDGES * sizeof(int) + 4095) & ~(size_t)4095;
  int* bucketCount = (int*)(ws + off);
  int* bucketStart = bucketCount + 128;
  int* cursor = bucketStart + 256;
  off += 4096;
  short* w1h = (short*)(ws + off); off += 8192 * sizeof(short);
  short* w1l = (short*)(ws + off); off += 8192 * sizeof(short);
  short* w2h = (short*)(ws + off); off += 8192 * sizeof(short);
  short* w2l = (short*)(ws + off); off += 8192 * sizeof(short);
  off = (off + 4095) & ~(size_t)4095;
  unsigned long long* pairBuf = (unsigned long long*)(ws + off);
  float* aggbuf = (float*)(ws + off);  // union: pairBuf dead before first sage_agg

  hipMemsetAsync(bucketCount, 0, NB * sizeof(int), stream);

  // ---- W pre-swizzle (independent of CSR) ----
  w_swizzle<<<32, 256, 0, stream>>>(W1, w1h, w1l);
  w_swizzle<<<32, 256, 0, stream>>>(W2, w2h, w2l);

  // ---- CSR build: bucketed two-phase partition ----
  p1_count<<<P1_BLOCKS, 256, 0, stream>>>(row, bucketCount);
  p1_scan<<<1, 128, 0, stream>>>(bucketCount, bucketStart, cursor);
  p1_scatter<<<P1_BLOCKS, 256, 0, stream>>>(row, col, cursor, pairBuf);
  p2_csr<<<NB, 1024, 0, stream>>>(pairBuf, bucketStart, endsArr, sortedCol);

  // ---- Layer 1: h = relu(concat(x, mean(x)) @ W1 + b1), h in d_out ----
  sage_agg<<<2048, 256, 0, stream>>>(x, endsArr, sortedCol, aggbuf, N_NODES);
  sage_mm<<<1024, 256, 0, stream>>>(x, aggbuf, w1h, w1l, b1, out, 1);

  // ---- Layer 2: out = concat(h, mean(h)) @ W2 + b2 (in place over h) ----
  sage_agg<<<2048, 256, 0, stream>>>(out, endsArr, sortedCol, aggbuf, N_NODES);
  sage_mm<<<1024, 256, 0, stream>>>(out, aggbuf, w2h, w2l, b2, out, 0);
}